// Round 5
// baseline (229.880 us; speedup 1.0000x reference)
//
#include <hip/hip_runtime.h>

// Problem constants: B=4, C=3, H=512, W=960, K2=16 -> K=4
#define BB 4
#define CC 3
#define HH 512
#define WW 960
#define HW (HH * WW)

// Fat blocks: 960 threads (15 waves), tile = 240x4 pixels, 1 px/thread.
// -> 2 blocks/CU = 30 waves/CU static occupancy; all global streams
// (filter/flow/store: 960B per tap-row; staging: 1KB per row-channel)
// are ~1KB contiguous segments instead of 256B.
#define TW 240
#define TH 4
#define NTX (WW / TW)            // 4
#define NTY (HH / TH)            // 128
#define NBLK (BB * NTX * NTY)    // 2048 (% 8 == 0 for XCD swizzle)
#define NTHREADS 960

// Staged window: 16 rows x 256 cols x 3 ch, all columns in-bounds
// (sx0 = clamp(x0-8, 0, 704)), so NO x-clamping at stage time and no
// scalar edge path. Row layout: [ch0 c0..255][ch1][ch2][pad chunk]
// = 193 chunks = 772 floats. 772 mod 32 = 4 -> row-deltas k=1..7 hit
// distinct banks (decorrelates per-lane floor(fy) jitter).
#define SROWS 16
#define SCOLS 256
#define CH_STRIDE 256
#define CHUNKS_PER_ROW 193
#define RSTRIDE 772
// 4 full-exec DMA rounds of 960 chunks; slots past 16*193=3088 are junk
// (valid duplicate sources, never read). No partial-exec DMA waves.
#define LDS_CHUNKS (4 * NTHREADS)         // 3840
#define LDS_FLOATS (LDS_CHUNKS * 4)       // 15360 floats = 61440 B

typedef __attribute__((address_space(1))) const unsigned int gu32;
typedef __attribute__((address_space(3))) unsigned int lu32;

__global__ __launch_bounds__(NTHREADS)
void filter_interp_kernel(const float* __restrict__ inp,
                          const float* __restrict__ flow,
                          const float* __restrict__ filt,
                          float* __restrict__ out) {
    __shared__ float lds[LDS_FLOATS];

    // Bijective XCD-aware swizzle (2048 % 8 == 0), ty-fastest -> each XCD
    // works contiguous vertical strips (L2-resident input slice).
    const int bid = blockIdx.x;
    const int lid = (bid & 7) * (NBLK / 8) + (bid >> 3);
    const int b   = lid >> 9;          // / (NTX*NTY) = /512
    const int rr  = lid & 511;
    const int tx  = rr >> 7;           // / NTY
    const int ty  = rr & 127;
    const int x0  = tx * TW;
    const int y0  = ty * TH;
    const int sx0 = min(max(x0 - 8, 0), WW - SCOLS);   // staged col origin

    const int tid  = threadIdx.x;
    const int wave = tid >> 6;

    const float* ibase = inp  + (size_t)b * CC * HW;
    const float* fbase = filt + (size_t)b * 16 * HW;
    const float* flbx  = flow + (size_t)(b * 2 + 0) * HW;
    const float* flby  = flow + (size_t)(b * 2 + 1) * HW;
    float*       obase = out  + (size_t)b * CC * HW;

    // ---- Stage 16x256x3 window via async DMA (4 full-exec rounds) ----
    // Dest = wave-uniform base + lane*16B (linear chunk order); per-lane
    // SOURCE encodes layout. All sources in-bounds: rows clamp via grow,
    // cols always valid by sx0 construction.
#pragma unroll
    for (int u = 0; u < 4; ++u) {
        const int c   = u * NTHREADS + tid;
        const int row = c / CHUNKS_PER_ROW;              // 0..19 (>=16: junk)
        const int cc  = c - row * CHUNKS_PER_ROW;
        int ch, t4;
        if (cc < 192) { ch = cc >> 6; t4 = cc & 63; }
        else          { ch = 0;       t4 = 0; }          // pad: dup source
        const int grow = min(max(y0 - 5 + row, 0), HH - 1);
        const float* src = ibase + (size_t)ch * HW +
                           (size_t)grow * WW + (sx0 + t4 * 4);
        lu32* dst = (lu32*)(void*)&lds[(u * NTHREADS + wave * 64) * 4];
        __builtin_amdgcn_global_load_lds((gu32*)(const void*)src, dst, 16, 0, 0);
    }

    // ---- Hoist flow + filter loads (fly across the barrier drain) ----
    const int p  = tid;                 // 1 px/thread
    const int py = p / TW;
    const int px = p - py * TW;
    const int x  = x0 + px;
    const int y  = y0 + py;
    const int rem = y * WW + x;

    const float fx = flbx[rem];
    const float fy = flby[rem];

    float f[16];
    {
        const float* fp = fbase + rem;
#pragma unroll
        for (int k = 0; k < 16; ++k) f[k] = fp[(size_t)k * HW];
    }

    __syncthreads();   // vmcnt(0) here drains DMA + register loads

    float acc0 = 0.0f, acc1 = 0.0f, acc2 = 0.0f;

    const float x2 = (float)x + fx;
    const float y2 = (float)y + fy;
    const bool valid = (x2 >= 0.0f) && (x2 <= (float)(WW - 1)) &&
                       (y2 >= 0.0f) && (y2 <= (float)(HH - 1)) &&
                       (fabsf(fx) < (float)WW * 0.5f) &&
                       (fabsf(fy) < (float)HH * 0.5f);

    if (valid) {
        const int ix = (int)floorf(x2);
        const int iy = (int)floorf(y2);
        const float alpha = x2 - (float)ix;
        const float beta  = y2 - (float)iy;

        const float wTL = (1.0f - alpha) * (1.0f - beta);
        const float wTR = alpha * (1.0f - beta);
        const float wBL = (1.0f - alpha) * beta;
        const float wBR = alpha * beta;

        // Fold 16 taps x 4 bilinear weights into 5x5 (channel-independent).
        float Wm[5][5];
#pragma unroll
        for (int j = 0; j < 5; ++j)
#pragma unroll
            for (int i = 0; i < 5; ++i) Wm[j][i] = 0.0f;
#pragma unroll
        for (int dj = 0; dj < 4; ++dj) {
#pragma unroll
            for (int di = 0; di < 4; ++di) {
                const float fv = f[dj * 4 + di];
                Wm[dj][di]         += fv * wTL;
                Wm[dj][di + 1]     += fv * wTR;
                Wm[dj + 1][di]     += fv * wBL;
                Wm[dj + 1][di + 1] += fv * wBR;
            }
        }

        const int ixL0 = ix - 1;
        const int iyT0 = iy - 1;
        const int cs = ixL0 - sx0;        // col slot of window start
        const int rs = iyT0 - (y0 - 5);   // row slot of window start

        // Fast path valid iff window fully inside staged region (which is
        // itself fully inside [0,W-1], so no x-clamp semantics needed).
        if ((unsigned)rs <= (unsigned)(SROWS - 5) &&
            (unsigned)cs <= (unsigned)(SCOLS - 6)) {
            // b64 gather; window aligned down to even col e0; 3 float2 per
            // row/channel; weight row barrel-shifted by o = cs&1.
            const int o  = cs & 1;
            const int e0 = cs - o;
            const float* lbase = lds + rs * RSTRIDE + e0;
#pragma unroll
            for (int j = 0; j < 5; ++j) {
                const float* lr = lbase + j * RSTRIDE;
                const float w0 = o ? 0.0f     : Wm[j][0];
                const float w1 = o ? Wm[j][0] : Wm[j][1];
                const float w2 = o ? Wm[j][1] : Wm[j][2];
                const float w3 = o ? Wm[j][2] : Wm[j][3];
                const float w4 = o ? Wm[j][3] : Wm[j][4];
                const float w5 = o ? Wm[j][4] : 0.0f;

                const float2 a0 = *(const float2*)(lr);
                const float2 a1 = *(const float2*)(lr + 2);
                const float2 a2 = *(const float2*)(lr + 4);
                acc0 += a0.x * w0 + a0.y * w1 + a1.x * w2 +
                        a1.y * w3 + a2.x * w4 + a2.y * w5;

                const float2 b0 = *(const float2*)(lr + CH_STRIDE);
                const float2 b1 = *(const float2*)(lr + CH_STRIDE + 2);
                const float2 b2 = *(const float2*)(lr + CH_STRIDE + 4);
                acc1 += b0.x * w0 + b0.y * w1 + b1.x * w2 +
                        b1.y * w3 + b2.x * w4 + b2.y * w5;

                const float2 c0 = *(const float2*)(lr + 2 * CH_STRIDE);
                const float2 c1 = *(const float2*)(lr + 2 * CH_STRIDE + 2);
                const float2 c2 = *(const float2*)(lr + 2 * CH_STRIDE + 4);
                acc2 += c0.x * w0 + c0.y * w1 + c1.x * w2 +
                        c1.y * w3 + c2.x * w4 + c2.y * w5;
            }
        } else {
            // Rare fallback (window crosses staged/image border, or |flow|
            // beyond margin): scalar clamped global gathers (verified logic).
            int R[5], S[5];
#pragma unroll
            for (int j = 0; j < 5; ++j) R[j] = min(max(iyT0 + j, 0), HH - 1);
#pragma unroll
            for (int i = 0; i < 5; ++i) S[i] = min(max(ixL0 + i, 0), WW - 1);
#pragma unroll
            for (int j = 0; j < 5; ++j) {
                const float* r0p = ibase + (size_t)R[j] * WW;
#pragma unroll
                for (int i = 0; i < 5; ++i) {
                    const float w = Wm[j][i];
                    const size_t oo = (size_t)S[i];
                    acc0 += r0p[oo] * w;
                    acc1 += r0p[HW + oo] * w;
                    acc2 += r0p[2 * (size_t)HW + oo] * w;
                }
            }
        }
    }

    obase[rem]          = acc0;
    obase[rem + HW]     = acc1;
    obase[rem + 2 * HW] = acc2;
}

extern "C" void kernel_launch(void* const* d_in, const int* in_sizes, int n_in,
                              void* d_out, int out_size, void* d_ws, size_t ws_size,
                              hipStream_t stream) {
    const float* teninput  = (const float*)d_in[0];
    const float* tenflow   = (const float*)d_in[1];
    const float* tenfilter = (const float*)d_in[2];
    float* out = (float*)d_out;

    filter_interp_kernel<<<NBLK, NTHREADS, 0, stream>>>(teninput, tenflow, tenfilter, out);
}

// Round 6
// 218.836 us; speedup vs baseline: 1.0505x; 1.0505x over previous
//
#include <hip/hip_runtime.h>

// Problem constants: B=4, C=3, H=512, W=960, K2=16 -> K=4
#define BB 4
#define CC 3
#define HH 512
#define WW 960
#define HW (HH * WW)
#define NPIX (BB * HW)

// 2D tiling: 64x4 pixels per 256-thread block (round-2 best structure)
#define TW 64
#define TH 4
#define NTX (WW / TW)          // 15
#define NTY (HH / TH)          // 128
#define NBLK (BB * NTX * NTY)  // 7680

// Staged input tile: rows y0-5 .. y0+10 (16), cols x0-8 .. x0+71 (80), 3 ch.
// Layout [s][ch][t], UNPADDED stride 80 -> linear in load index, so interior
// staging can use global_load_lds (wave-uniform base + lane*16B).
#define ROWS 16
#define COLS 80
#define RSTRIDE (CC * COLS)             // 240 floats per staged row
#define LDS_FLOATS (ROWS * RSTRIDE)     // 3840 floats = 15360 B

typedef __attribute__((address_space(1))) const unsigned int gu32;
typedef __attribute__((address_space(3))) unsigned int lu32;

__global__ __launch_bounds__(256, 4)
void filter_interp_kernel(const float* __restrict__ inp,
                          const float* __restrict__ flow,
                          const float* __restrict__ filt,
                          float* __restrict__ out) {
    __shared__ float lds[LDS_FLOATS];

    // Bijective XCD-aware swizzle (NBLK % 8 == 0): ty-fastest -> each XCD
    // works a contiguous vertical strip; input slice fits its L2.
    const int bid = blockIdx.x;
    const int swz = (bid & 7) * (NBLK / 8) + (bid >> 3);
    const int b   = swz / (NTX * NTY);
    const int rr  = swz - b * (NTX * NTY);
    const int tx  = rr / NTY;
    const int ty  = rr - tx * NTY;
    const int x0  = tx * TW;
    const int y0  = ty * TH;

    const int tid  = threadIdx.x;
    const int wave = tid >> 6;
    const float* ibase = inp + (size_t)b * CC * HW;

    // ---- Stage input tile into LDS ----
    if (tx > 0 && tx < NTX - 1) {
        // Interior in x: async DMA straight to LDS, no VGPR round-trip.
#pragma unroll
        for (int e = 0; e < 4; ++e) {
            const int idx = e * 256 + tid;
            if (idx < ROWS * CC * (COLS / 4)) {          // 960 float4s
                const int s  = idx / 60;                 // CC*(COLS/4)
                const int r2 = idx - s * 60;
                const int ch = r2 / 20;                  // COLS/4
                const int t4 = r2 - ch * 20;
                const int grow = min(max(y0 - 5 + s, 0), HH - 1);
                const float* src = ibase + (size_t)ch * HW +
                                   (size_t)grow * WW + (x0 - 8 + t4 * 4);
                lu32* dst = (lu32*)(void*)&lds[(e * 256 + wave * 64) * 4];
                __builtin_amdgcn_global_load_lds((gu32*)(const void*)src,
                                                 dst, 16, 0, 0);
            }
        }
    } else {
        // x-edge tile: scalar loads with per-column clamp.
#pragma unroll
        for (int e = 0; e < 15; ++e) {
            const int idx = e * 256 + tid;               // exactly 3840 total
            const int s  = idx / RSTRIDE;
            const int r2 = idx - s * RSTRIDE;
            const int ch = r2 / COLS;
            const int t  = r2 - ch * COLS;
            const int grow = min(max(y0 - 5 + s, 0), HH - 1);
            const int gcol = min(max(x0 - 8 + t, 0), WW - 1);
            lds[idx] = ibase[(size_t)ch * HW + (size_t)grow * WW + gcol];
        }
    }

    // ---- Hoist flow + filter loads so they fly across the barrier ----
    const int lx = tid & (TW - 1);
    const int wy = tid >> 6;
    const int x  = x0 + lx;
    const int y  = y0 + wy;
    const int rem = y * WW + x;

    const float fx = flow[(size_t)(b * 2 + 0) * HW + rem];
    const float fy = flow[(size_t)(b * 2 + 1) * HW + rem];

    float f[16];
    {
        const float* fptr = filt + (size_t)b * 16 * HW + rem;
#pragma unroll
        for (int k = 0; k < 16; ++k) f[k] = fptr[(size_t)k * HW];
    }

    __syncthreads();   // vmcnt(0) here also drains the global_load_lds DMA

    const float x2 = (float)x + fx;
    const float y2 = (float)y + fy;

    const bool valid = (x2 >= 0.0f) && (x2 <= (float)(WW - 1)) &&
                       (y2 >= 0.0f) && (y2 <= (float)(HH - 1)) &&
                       (fabsf(fx) < (float)WW * 0.5f) &&
                       (fabsf(fy) < (float)HH * 0.5f);

    float acc0 = 0.0f, acc1 = 0.0f, acc2 = 0.0f;

    if (valid) {
        const int ix = (int)floorf(x2);
        const int iy = (int)floorf(y2);
        const float alpha = x2 - (float)ix;
        const float beta  = y2 - (float)iy;

        const float wTL = (1.0f - alpha) * (1.0f - beta);
        const float wTR = alpha * (1.0f - beta);
        const float wBL = (1.0f - alpha) * beta;
        const float wBR = alpha * beta;

        // Fold 16 taps x 4 bilinear weights into 5x5 (channel-independent).
        float Wm[5][5];
#pragma unroll
        for (int j = 0; j < 5; ++j)
#pragma unroll
            for (int i = 0; i < 5; ++i) Wm[j][i] = 0.0f;
#pragma unroll
        for (int dj = 0; dj < 4; ++dj) {
#pragma unroll
            for (int di = 0; di < 4; ++di) {
                const float fv = f[dj * 4 + di];
                Wm[dj][di]         += fv * wTL;
                Wm[dj][di + 1]     += fv * wTR;
                Wm[dj + 1][di]     += fv * wBL;
                Wm[dj + 1][di + 1] += fv * wBR;
            }
        }

        const int ixL0 = ix - 1;
        const int iyT0 = iy - 1;
        const int cs = ixL0 - (x0 - 8);   // col slot of window start
        const int rs = iyT0 - (y0 - 5);   // row slot of window start

        if ((unsigned)rs <= (unsigned)(ROWS - 5) &&
            (unsigned)cs <= (unsigned)(COLS - 5)) {
            // Fast path: b64 gather, STALL-COLLAPSED SCHEDULE.
            // Batch the ds_reads into register arrays (rows 0-2, then rows
            // 3-4), each batch fenced by sched_barrier(0), so each batch
            // issues back-to-back and incurs ONE lgkm wait instead of ~15
            // read->use stalls. All indices compile-time -> registers.
            const int o  = cs & 1;
            const int e0 = cs - o;
            const float* lbase = lds + rs * RSTRIDE + e0;

            // Shifted 6-wide weight rows (shift amount o common to all rows).
            float Ws[5][6];
#pragma unroll
            for (int j = 0; j < 5; ++j) {
                Ws[j][0] = o ? 0.0f     : Wm[j][0];
                Ws[j][1] = o ? Wm[j][0] : Wm[j][1];
                Ws[j][2] = o ? Wm[j][1] : Wm[j][2];
                Ws[j][3] = o ? Wm[j][2] : Wm[j][3];
                Ws[j][4] = o ? Wm[j][3] : Wm[j][4];
                Ws[j][5] = o ? Wm[j][4] : 0.0f;
            }

            // ---- Batch 1: rows 0..2 (27 float2 = 54 VGPR) ----
            float2 v1[3][3][3];
#pragma unroll
            for (int j = 0; j < 3; ++j) {
                const float* lr = lbase + j * RSTRIDE;
#pragma unroll
                for (int ch = 0; ch < 3; ++ch)
#pragma unroll
                    for (int k = 0; k < 3; ++k)
                        v1[j][ch][k] = *(const float2*)(lr + ch * COLS + 2 * k);
            }
            __builtin_amdgcn_sched_barrier(0);
#pragma unroll
            for (int j = 0; j < 3; ++j) {
                acc0 += v1[j][0][0].x * Ws[j][0] + v1[j][0][0].y * Ws[j][1] +
                        v1[j][0][1].x * Ws[j][2] + v1[j][0][1].y * Ws[j][3] +
                        v1[j][0][2].x * Ws[j][4] + v1[j][0][2].y * Ws[j][5];
                acc1 += v1[j][1][0].x * Ws[j][0] + v1[j][1][0].y * Ws[j][1] +
                        v1[j][1][1].x * Ws[j][2] + v1[j][1][1].y * Ws[j][3] +
                        v1[j][1][2].x * Ws[j][4] + v1[j][1][2].y * Ws[j][5];
                acc2 += v1[j][2][0].x * Ws[j][0] + v1[j][2][0].y * Ws[j][1] +
                        v1[j][2][1].x * Ws[j][2] + v1[j][2][1].y * Ws[j][3] +
                        v1[j][2][2].x * Ws[j][4] + v1[j][2][2].y * Ws[j][5];
            }
            __builtin_amdgcn_sched_barrier(0);

            // ---- Batch 2: rows 3..4 (18 float2 = 36 VGPR) ----
            float2 v2[2][3][3];
#pragma unroll
            for (int j = 0; j < 2; ++j) {
                const float* lr = lbase + (j + 3) * RSTRIDE;
#pragma unroll
                for (int ch = 0; ch < 3; ++ch)
#pragma unroll
                    for (int k = 0; k < 3; ++k)
                        v2[j][ch][k] = *(const float2*)(lr + ch * COLS + 2 * k);
            }
            __builtin_amdgcn_sched_barrier(0);
#pragma unroll
            for (int j = 0; j < 2; ++j) {
                const int jj = j + 3;
                acc0 += v2[j][0][0].x * Ws[jj][0] + v2[j][0][0].y * Ws[jj][1] +
                        v2[j][0][1].x * Ws[jj][2] + v2[j][0][1].y * Ws[jj][3] +
                        v2[j][0][2].x * Ws[jj][4] + v2[j][0][2].y * Ws[jj][5];
                acc1 += v2[j][1][0].x * Ws[jj][0] + v2[j][1][0].y * Ws[jj][1] +
                        v2[j][1][1].x * Ws[jj][2] + v2[j][1][1].y * Ws[jj][3] +
                        v2[j][1][2].x * Ws[jj][4] + v2[j][1][2].y * Ws[jj][5];
                acc2 += v2[j][2][0].x * Ws[jj][0] + v2[j][2][0].y * Ws[jj][1] +
                        v2[j][2][1].x * Ws[jj][2] + v2[j][2][1].y * Ws[jj][3] +
                        v2[j][2][2].x * Ws[jj][4] + v2[j][2][2].y * Ws[jj][5];
            }
        } else {
            // Rare fallback (|flow| beyond tile margin but still valid):
            // scalar clamped global gathers, same math as verified slow path.
            int R[5], S[5];
#pragma unroll
            for (int j = 0; j < 5; ++j) R[j] = min(max(iyT0 + j, 0), HH - 1);
#pragma unroll
            for (int i = 0; i < 5; ++i) S[i] = min(max(ixL0 + i, 0), WW - 1);
#pragma unroll
            for (int j = 0; j < 5; ++j) {
                const float* r0 = ibase + (size_t)R[j] * WW;
#pragma unroll
                for (int i = 0; i < 5; ++i) {
                    const float w = Wm[j][i];
                    const size_t oidx = (size_t)S[i];
                    acc0 += r0[oidx] * w;
                    acc1 += r0[HW + oidx] * w;
                    acc2 += r0[2 * (size_t)HW + oidx] * w;
                }
            }
        }
    }

    const int outbase = b * CC * HW + rem;
    out[outbase]          = acc0;
    out[outbase + HW]     = acc1;
    out[outbase + 2 * HW] = acc2;
}

extern "C" void kernel_launch(void* const* d_in, const int* in_sizes, int n_in,
                              void* d_out, int out_size, void* d_ws, size_t ws_size,
                              hipStream_t stream) {
    const float* teninput  = (const float*)d_in[0];
    const float* tenflow   = (const float*)d_in[1];
    const float* tenfilter = (const float*)d_in[2];
    float* out = (float*)d_out;

    filter_interp_kernel<<<NBLK, 256, 0, stream>>>(teninput, tenflow, tenfilter, out);
}

// Round 7
// 217.089 us; speedup vs baseline: 1.0589x; 1.0080x over previous
//
#include <hip/hip_runtime.h>

// Problem constants: B=4, C=3, H=512, W=960, K2=16 -> K=4
#define BB 4
#define CC 3
#define HH 512
#define WW 960
#define HW (HH * WW)

// 2D tiling: 64x4 pixels per 256-thread block (round-2 best structure)
#define TW 64
#define TH 4
#define NTX (WW / TW)          // 15
#define NTY (HH / TH)          // 128
#define NBLK (BB * NTX * NTY)  // 7680

// Staged input tile: rows y0-5 .. y0+10 (16), cols x0-8 .. x0+71 (80), 3 ch.
// Layout [s][ch][t], UNPADDED stride 80 -> linear in load index, so interior
// staging can use global_load_lds (wave-uniform base + lane*16B).
#define ROWS 16
#define COLS 80
#define RSTRIDE (CC * COLS)             // 240 floats per staged row
#define LDS_IN_FLOATS (ROWS * RSTRIDE)  // 3840 floats = 15360 B

// Filter/flow also staged via DMA: cuts per-block VMEM wave-instructions
// from ~99 to ~45 (filter 64 -> 16, flow 8 -> 2). Layout [k][px] so the
// post-barrier per-thread read lds_f[k*256 + tid] is conflict-free
// (consecutive lanes -> consecutive banks).
#define LDS_F_FLOATS (16 * 256)         // 16384 B
#define LDS_FL_FLOATS (2 * 256)         // 2048 B

typedef __attribute__((address_space(1))) const unsigned int gu32;
typedef __attribute__((address_space(3))) unsigned int lu32;

__global__ __launch_bounds__(256)
void filter_interp_kernel(const float* __restrict__ inp,
                          const float* __restrict__ flow,
                          const float* __restrict__ filt,
                          float* __restrict__ out) {
    __shared__ float lds[LDS_IN_FLOATS];
    __shared__ float lds_f[LDS_F_FLOATS];
    __shared__ float lds_fl[LDS_FL_FLOATS];

    // Bijective XCD-aware swizzle (NBLK % 8 == 0): ty-fastest -> each XCD
    // works a contiguous vertical strip; input slice fits its L2.
    const int bid = blockIdx.x;
    const int swz = (bid & 7) * (NBLK / 8) + (bid >> 3);
    const int b   = swz / (NTX * NTY);
    const int rr  = swz - b * (NTX * NTY);
    const int tx  = rr / NTY;
    const int ty  = rr - tx * NTY;
    const int x0  = tx * TW;
    const int y0  = ty * TH;

    const int tid  = threadIdx.x;
    const int wave = tid >> 6;
    const float* ibase = inp  + (size_t)b * CC * HW;
    const float* fbase = filt + (size_t)b * 16 * HW;

    // ---- Stage input tile into LDS (identical to round-2) ----
    if (tx > 0 && tx < NTX - 1) {
        // Interior in x: async DMA straight to LDS, no VGPR round-trip.
#pragma unroll
        for (int e = 0; e < 4; ++e) {
            const int idx = e * 256 + tid;
            if (idx < ROWS * CC * (COLS / 4)) {          // 960 float4s
                const int s  = idx / 60;                 // CC*(COLS/4)
                const int r2 = idx - s * 60;
                const int ch = r2 / 20;                  // COLS/4
                const int t4 = r2 - ch * 20;
                const int grow = min(max(y0 - 5 + s, 0), HH - 1);
                const float* src = ibase + (size_t)ch * HW +
                                   (size_t)grow * WW + (x0 - 8 + t4 * 4);
                lu32* dst = (lu32*)(void*)&lds[(e * 256 + wave * 64) * 4];
                __builtin_amdgcn_global_load_lds((gu32*)(const void*)src,
                                                 dst, 16, 0, 0);
            }
        }
    } else {
        // x-edge tile: scalar loads with per-column clamp.
#pragma unroll
        for (int e = 0; e < 15; ++e) {
            const int idx = e * 256 + tid;               // exactly 3840 total
            const int s  = idx / RSTRIDE;
            const int r2 = idx - s * RSTRIDE;
            const int ch = r2 / COLS;
            const int t  = r2 - ch * COLS;
            const int grow = min(max(y0 - 5 + s, 0), HH - 1);
            const int gcol = min(max(x0 - 8 + t, 0), WW - 1);
            lds[idx] = ibase[(size_t)ch * HW + (size_t)grow * WW + gcol];
        }
    }

    // ---- Stage filter (16 KB, 16 DMA instrs/block) and flow (2 KB, 2) ----
    // Tap k's tile slab filt[b][k][y0..y0+3][x0..x0+63] = 1KB: lane l loads
    // 16B at (row y0 + l/16, col x0 + (l%16)*4); dest linear [k][row][col].
    const int l    = tid & 63;
    const int frow = l >> 4;           // 0..3
    const int fcol = (l & 15) << 2;    // 0..60
    const float* fsrc = fbase + (size_t)(y0 + frow) * WW + (x0 + fcol);
#pragma unroll
    for (int q = 0; q < 4; ++q) {
        const int k = (wave << 2) + q;                 // wave w -> taps 4w..4w+3
        const float* src = fsrc + (size_t)k * HW;
        lu32* dst = (lu32*)(void*)&lds_f[k << 8];
        __builtin_amdgcn_global_load_lds((gu32*)(const void*)src, dst, 16, 0, 0);
    }
    if (wave < 2) {                                    // wave-uniform branch
        const float* src = flow + (size_t)(b * 2 + wave) * HW +
                           (size_t)(y0 + frow) * WW + (x0 + fcol);
        lu32* dst = (lu32*)(void*)&lds_fl[wave << 8];
        __builtin_amdgcn_global_load_lds((gu32*)(const void*)src, dst, 16, 0, 0);
    }

    __syncthreads();   // vmcnt(0) here drains all DMA

    const int lx = tid & (TW - 1);
    const int wy = tid >> 6;
    const int x  = x0 + lx;
    const int y  = y0 + wy;
    const int rem = y * WW + x;

    // Flow + filter now come from LDS (conflict-free: lanes consecutive).
    const float fx = lds_fl[tid];
    const float fy = lds_fl[256 + tid];

    float f[16];
#pragma unroll
    for (int k = 0; k < 16; ++k) f[k] = lds_f[(k << 8) + tid];

    const float x2 = (float)x + fx;
    const float y2 = (float)y + fy;

    const bool valid = (x2 >= 0.0f) && (x2 <= (float)(WW - 1)) &&
                       (y2 >= 0.0f) && (y2 <= (float)(HH - 1)) &&
                       (fabsf(fx) < (float)WW * 0.5f) &&
                       (fabsf(fy) < (float)HH * 0.5f);

    float acc0 = 0.0f, acc1 = 0.0f, acc2 = 0.0f;

    if (valid) {
        const int ix = (int)floorf(x2);
        const int iy = (int)floorf(y2);
        const float alpha = x2 - (float)ix;
        const float beta  = y2 - (float)iy;

        const float wTL = (1.0f - alpha) * (1.0f - beta);
        const float wTR = alpha * (1.0f - beta);
        const float wBL = (1.0f - alpha) * beta;
        const float wBR = alpha * beta;

        // Fold 16 taps x 4 bilinear weights into 5x5 (channel-independent).
        float Wm[5][5];
#pragma unroll
        for (int j = 0; j < 5; ++j)
#pragma unroll
            for (int i = 0; i < 5; ++i) Wm[j][i] = 0.0f;
#pragma unroll
        for (int dj = 0; dj < 4; ++dj) {
#pragma unroll
            for (int di = 0; di < 4; ++di) {
                const float fv = f[dj * 4 + di];
                Wm[dj][di]         += fv * wTL;
                Wm[dj][di + 1]     += fv * wTR;
                Wm[dj + 1][di]     += fv * wBL;
                Wm[dj + 1][di + 1] += fv * wBR;
            }
        }

        const int ixL0 = ix - 1;
        const int iyT0 = iy - 1;
        const int cs = ixL0 - (x0 - 8);   // col slot of window start
        const int rs = iyT0 - (y0 - 5);   // row slot of window start

        if ((unsigned)rs <= (unsigned)(ROWS - 5) &&
            (unsigned)cs <= (unsigned)(COLS - 5)) {
            // Fast path: b64 gather from LDS (round-2 schedule, unchanged).
            const int o  = cs & 1;
            const int e0 = cs - o;
            const float* lbase = lds + rs * RSTRIDE + e0;
#pragma unroll
            for (int j = 0; j < 5; ++j) {
                const float* lr = lbase + j * RSTRIDE;
                const float w0 = o ? 0.0f     : Wm[j][0];
                const float w1 = o ? Wm[j][0] : Wm[j][1];
                const float w2 = o ? Wm[j][1] : Wm[j][2];
                const float w3 = o ? Wm[j][2] : Wm[j][3];
                const float w4 = o ? Wm[j][3] : Wm[j][4];
                const float w5 = o ? Wm[j][4] : 0.0f;

                const float2 a0 = *(const float2*)(lr);
                const float2 a1 = *(const float2*)(lr + 2);
                const float2 a2 = *(const float2*)(lr + 4);
                acc0 += a0.x * w0 + a0.y * w1 + a1.x * w2 +
                        a1.y * w3 + a2.x * w4 + a2.y * w5;

                const float2 b0 = *(const float2*)(lr + COLS);
                const float2 b1 = *(const float2*)(lr + COLS + 2);
                const float2 b2 = *(const float2*)(lr + COLS + 4);
                acc1 += b0.x * w0 + b0.y * w1 + b1.x * w2 +
                        b1.y * w3 + b2.x * w4 + b2.y * w5;

                const float2 c0 = *(const float2*)(lr + 2 * COLS);
                const float2 c1 = *(const float2*)(lr + 2 * COLS + 2);
                const float2 c2 = *(const float2*)(lr + 2 * COLS + 4);
                acc2 += c0.x * w0 + c0.y * w1 + c1.x * w2 +
                        c1.y * w3 + c2.x * w4 + c2.y * w5;
            }
        } else {
            // Rare fallback (|flow| beyond tile margin but still valid):
            // scalar clamped global gathers, same math as verified slow path.
            int R[5], S[5];
#pragma unroll
            for (int j = 0; j < 5; ++j) R[j] = min(max(iyT0 + j, 0), HH - 1);
#pragma unroll
            for (int i = 0; i < 5; ++i) S[i] = min(max(ixL0 + i, 0), WW - 1);
#pragma unroll
            for (int j = 0; j < 5; ++j) {
                const float* r0 = ibase + (size_t)R[j] * WW;
#pragma unroll
                for (int i = 0; i < 5; ++i) {
                    const float w = Wm[j][i];
                    const size_t oidx = (size_t)S[i];
                    acc0 += r0[oidx] * w;
                    acc1 += r0[HW + oidx] * w;
                    acc2 += r0[2 * (size_t)HW + oidx] * w;
                }
            }
        }
    }

    const int outbase = b * CC * HW + rem;
    out[outbase]          = acc0;
    out[outbase + HW]     = acc1;
    out[outbase + 2 * HW] = acc2;
}

extern "C" void kernel_launch(void* const* d_in, const int* in_sizes, int n_in,
                              void* d_out, int out_size, void* d_ws, size_t ws_size,
                              hipStream_t stream) {
    const float* teninput  = (const float*)d_in[0];
    const float* tenflow   = (const float*)d_in[1];
    const float* tenfilter = (const float*)d_in[2];
    float* out = (float*)d_out;

    filter_interp_kernel<<<NBLK, 256, 0, stream>>>(teninput, tenflow, tenfilter, out);
}